// Round 3
// baseline (12859.300 us; speedup 1.0000x reference)
//
#include <hip/hip_runtime.h>
#include <math.h>

#define BB 16
#define CC 256
#define NN 2048
#define HH 64
#define NEGV (-9.0e15f)

// ---------------------------------------------------------------------------
// GEMM: out[b, o, n] = sum_c W[o,c] * Xeff[b,c,n] + bias[o]
//   SUB=false: Xeff = X
//   SUB=true : Xeff = X - Y/(1e-9 + Ycol)   (Y is [B, C+1, N]; Ycol = row C)
// 64x64 output tile, 256 threads, 4x4 per thread, K-tile 16.
// ---------------------------------------------------------------------------
template<bool SUB>
__global__ __launch_bounds__(256)
void gemm_wx(const float* __restrict__ W, const float* __restrict__ X,
             const float* __restrict__ bias, const float* __restrict__ Y,
             float* __restrict__ out, long xStride, long oStride)
{
  const int n0 = blockIdx.x * 64;
  const int o0 = blockIdx.y * 64;
  const int b  = blockIdx.z;
  const int tid = threadIdx.x;
  const int tx = tid & 15, ty = tid >> 4;

  __shared__ float Wt[16][68];
  __shared__ float Xt[16][68];

  const float* Xb = X + (long)b * xStride;
  const float* Yb = Y + (long)b * (CC + 1) * NN;  // only dereferenced if SUB

  float acc[4][4] = {{0.f}};

  const int loW = tid >> 2;         // 0..63 (o row)
  const int kqW = (tid & 3) * 4;    // 0,4,8,12
  const int kkX = tid >> 4;         // 0..15
  const int nnX = (tid & 15) * 4;   // 0..60

  for (int k0 = 0; k0 < CC; k0 += 16) {
    float4 w4 = *(const float4*)&W[(long)(o0 + loW) * CC + k0 + kqW];
    float4 x4 = *(const float4*)&Xb[(long)(k0 + kkX) * NN + n0 + nnX];
    if (SUB) {
      float4 y4 = *(const float4*)&Yb[(long)(k0 + kkX) * NN + n0 + nnX];
      float4 cs = *(const float4*)&Yb[(long)CC * NN + n0 + nnX];
      x4.x -= y4.x / (1e-9f + cs.x);
      x4.y -= y4.y / (1e-9f + cs.y);
      x4.z -= y4.z / (1e-9f + cs.z);
      x4.w -= y4.w / (1e-9f + cs.w);
    }
    Wt[kqW+0][loW] = w4.x; Wt[kqW+1][loW] = w4.y;
    Wt[kqW+2][loW] = w4.z; Wt[kqW+3][loW] = w4.w;
    *(float4*)&Xt[kkX][nnX] = x4;
    __syncthreads();
    #pragma unroll
    for (int kk = 0; kk < 16; kk++) {
      const float4 a  = *(const float4*)&Wt[kk][ty*4];
      const float4 bv = *(const float4*)&Xt[kk][tx*4];
      const float av[4] = {a.x, a.y, a.z, a.w};
      const float bw[4] = {bv.x, bv.y, bv.z, bv.w};
      #pragma unroll
      for (int i = 0; i < 4; i++)
        #pragma unroll
        for (int j = 0; j < 4; j++)
          acc[i][j] += av[i] * bw[j];
    }
    __syncthreads();
  }

  float bs[4] = {0.f, 0.f, 0.f, 0.f};
  if (bias) {
    #pragma unroll
    for (int i = 0; i < 4; i++) bs[i] = bias[o0 + ty*4 + i];
  }
  #pragma unroll
  for (int i = 0; i < 4; i++) {
    float4 o;
    o.x = acc[i][0] + bs[i]; o.y = acc[i][1] + bs[i];
    o.z = acc[i][2] + bs[i]; o.w = acc[i][3] + bs[i];
    *(float4*)&out[(long)b * oStride + (long)(o0 + ty*4 + i) * NN + n0 + tx*4] = o;
  }
}

// ---------------------------------------------------------------------------
// rowstat: per (b, n): rowmax and 1/rowsum of masked energy row
//   S[n,m] = sum_h q[b,h,n]*q[b,h,m], masked to NEG if !(mask[n]&&mask[m])
// 16 rows per block, 16 lanes/row, online softmax over m-chunks of 64.
// ---------------------------------------------------------------------------
__global__ __launch_bounds__(256)
void rowstat_kernel(const float* __restrict__ q, const int* __restrict__ mask,
                    float* __restrict__ rmax, float* __restrict__ rinv)
{
  const int b  = blockIdx.y;
  const int n0 = blockIdx.x * 16;
  const int tid = threadIdx.x;
  const int r = tid >> 4, l = tid & 15;

  __shared__ float qn[16][68];
  __shared__ float qm[64][68];   // [h][mm]
  __shared__ int ml[64];

  for (int i = tid; i < 16*64; i += 256) {
    int h = i >> 4, rr = i & 15;
    qn[rr][h] = q[((long)b*HH + h) * NN + n0 + rr];
  }
  __syncthreads();

  float qr[64];
  #pragma unroll
  for (int i = 0; i < 16; i++) {
    const float4 t4 = *(const float4*)&qn[r][i*4];
    qr[i*4+0] = t4.x; qr[i*4+1] = t4.y; qr[i*4+2] = t4.z; qr[i*4+3] = t4.w;
  }
  const int rowm = mask[(long)b*NN + n0 + r];

  float mx = -INFINITY, sm = 0.f;

  for (int m0 = 0; m0 < NN; m0 += 64) {
    __syncthreads();
    for (int i = tid; i < 1024; i += 256) {
      int h = i >> 4, mm4 = (i & 15) * 4;
      *(float4*)&qm[h][mm4] = *(const float4*)&q[((long)b*HH + h) * NN + m0 + mm4];
    }
    if (tid < 64) ml[tid] = mask[(long)b*NN + m0 + tid];
    __syncthreads();

    float s0 = 0.f, s1 = 0.f, s2 = 0.f, s3 = 0.f;
    #pragma unroll
    for (int h = 0; h < 64; h++) {
      const float4 v = *(const float4*)&qm[h][l*4];
      const float a = qr[h];
      s0 += a*v.x; s1 += a*v.y; s2 += a*v.z; s3 += a*v.w;
    }
    const float sv[4] = {s0, s1, s2, s3};
    #pragma unroll
    for (int e = 0; e < 4; e++) {
      const float vm = (rowm && ml[l*4+e]) ? sv[e] : NEGV;
      const float nm = fmaxf(mx, vm);
      sm = sm * __expf(mx - nm) + __expf(vm - nm);
      mx = nm;
    }
  }

  #pragma unroll
  for (int off = 1; off < 16; off <<= 1) {
    const float om = __shfl_xor(mx, off, 64);
    const float os = __shfl_xor(sm, off, 64);
    const float nm = fmaxf(mx, om);
    sm = sm * __expf(mx - nm) + os * __expf(om - nm);
    mx = nm;
  }
  if (l == 0) {
    rmax[(long)b*NN + n0 + r] = mx;
    rinv[(long)b*NN + n0 + r] = 1.0f / sm;
  }
}

// ---------------------------------------------------------------------------
// yatt: Y[b,c,m] = sum_n xv[b,c,n] * Atil[n,m], c in [0,C); row C gets colsum.
//   Atil[n,m] = exp(S_masked[n,m] - rowmax[n]) * rowinv[n]  (recomputed from q)
// Block: one 32-wide m-tile, all 256 c rows. n streamed in chunks of 64.
// ---------------------------------------------------------------------------
__global__ __launch_bounds__(256)
void yatt_kernel(const float* __restrict__ q, const float* __restrict__ xv,
                 const int* __restrict__ mask,
                 const float* __restrict__ rmax, const float* __restrict__ rinv,
                 float* __restrict__ y)
{
  const int b  = blockIdx.y;
  const int m0 = blockIdx.x * 32;
  const int tid = threadIdx.x;

  __shared__ float qm[64][36];   // [h][m]
  __shared__ float qn[64][68];   // [h][n']
  __shared__ float at[32][68];   // [m][n']
  __shared__ float rml[64], ril[64];
  __shared__ int   mrow[64];
  __shared__ int   mcol[32];

  for (int i = tid; i < 64*32; i += 256) {
    int mm = i & 31, h = i >> 5;
    qm[h][mm] = q[((long)b*HH + h) * NN + m0 + mm];
  }
  if (tid < 32) mcol[tid] = mask[(long)b*NN + m0 + tid];

  const int an = tid & 15, am = tid >> 4;   // phase-A map: 4 n' x 2 m
  const int tm = tid & 7,  tc = tid >> 3;   // phase-B map: 8 c x 4 m
  const float* xvb = xv + (long)b * CC * NN;

  float acc[8][4] = {{0.f}};
  float csum[4] = {0.f, 0.f, 0.f, 0.f};

  for (int nc = 0; nc < NN; nc += 64) {
    __syncthreads();
    for (int i = tid; i < 64*64; i += 256) {
      int nn = i & 63, h = i >> 6;
      qn[h][nn] = q[((long)b*HH + h) * NN + nc + nn];
    }
    if (tid < 64) {
      rml[tid]  = rmax[(long)b*NN + nc + tid];
      ril[tid]  = rinv[(long)b*NN + nc + tid];
      mrow[tid] = mask[(long)b*NN + nc + tid];
    }
    __syncthreads();

    // phase A: energy tile + exp -> at[m][n']
    float sA[4][2] = {{0.f}};
    #pragma unroll
    for (int h = 0; h < 64; h++) {
      const float4 a  = *(const float4*)&qn[h][an*4];
      const float2 bq = *(const float2*)&qm[h][am*2];
      sA[0][0] += a.x*bq.x; sA[0][1] += a.x*bq.y;
      sA[1][0] += a.y*bq.x; sA[1][1] += a.y*bq.y;
      sA[2][0] += a.z*bq.x; sA[2][1] += a.z*bq.y;
      sA[3][0] += a.w*bq.x; sA[3][1] += a.w*bq.y;
    }
    #pragma unroll
    for (int i = 0; i < 4; i++) {
      const int nn = an*4 + i;
      const float rm = rml[nn], riv = ril[nn];
      const int rb = mrow[nn];
      #pragma unroll
      for (int j = 0; j < 2; j++) {
        const int mlc = am*2 + j;
        const float v = (rb && mcol[mlc]) ? sA[i][j] : NEGV;
        at[mlc][nn] = __expf(v - rm) * riv;
      }
    }
    __syncthreads();

    // phase B: acc[c][m] += xv[c][n'] * at[m][n']; tc==0 threads also colsum
    #pragma unroll 2
    for (int nq = 0; nq < 16; nq++) {
      const float4 av0 = *(const float4*)&at[tm*4+0][nq*4];
      const float4 av1 = *(const float4*)&at[tm*4+1][nq*4];
      const float4 av2 = *(const float4*)&at[tm*4+2][nq*4];
      const float4 av3 = *(const float4*)&at[tm*4+3][nq*4];
      if (tc == 0) {
        csum[0] += av0.x+av0.y+av0.z+av0.w;
        csum[1] += av1.x+av1.y+av1.z+av1.w;
        csum[2] += av2.x+av2.y+av2.z+av2.w;
        csum[3] += av3.x+av3.y+av3.z+av3.w;
      }
      #pragma unroll
      for (int i = 0; i < 8; i++) {
        const float4 xw = *(const float4*)&xvb[(long)(tc*8 + i) * NN + nc + nq*4];
        acc[i][0] += xw.x*av0.x + xw.y*av0.y + xw.z*av0.z + xw.w*av0.w;
        acc[i][1] += xw.x*av1.x + xw.y*av1.y + xw.z*av1.z + xw.w*av1.w;
        acc[i][2] += xw.x*av2.x + xw.y*av2.y + xw.z*av2.z + xw.w*av2.w;
        acc[i][3] += xw.x*av3.x + xw.y*av3.y + xw.z*av3.z + xw.w*av3.w;
      }
    }
  }

  float* yb = y + (long)b * (CC + 1) * NN;
  #pragma unroll
  for (int i = 0; i < 8; i++) {
    float4 o; o.x = acc[i][0]; o.y = acc[i][1]; o.z = acc[i][2]; o.w = acc[i][3];
    *(float4*)&yb[(long)(tc*8 + i) * NN + m0 + tm*4] = o;
  }
  if (tc == 0) {
    float4 o; o.x = csum[0]; o.y = csum[1]; o.z = csum[2]; o.w = csum[3];
    *(float4*)&yb[(long)CC * NN + m0 + tm*4] = o;
  }
}

// ---------------------------------------------------------------------------
// bnstats: one block per channel; mean & invstd over B*N (training-mode,
// biased variance). Deterministic (no atomics).
// ---------------------------------------------------------------------------
__global__ __launch_bounds__(1024)
void bnstats_kernel(const float* __restrict__ t,
                    float* __restrict__ mean, float* __restrict__ istd)
{
  const int c = blockIdx.x, tid = threadIdx.x;
  float s = 0.f, sq = 0.f;
  for (int f = tid; f < (BB*NN)/4; f += 1024) {
    const int b = f >> 9, n4 = f & 511;           // N/4 = 512
    const float4 v = *(const float4*)&t[((long)b*CC + c) * NN + n4*4];
    s  += v.x + v.y + v.z + v.w;
    sq += v.x*v.x + v.y*v.y + v.z*v.z + v.w*v.w;
  }
  for (int off = 32; off; off >>= 1) {
    s  += __shfl_down(s,  off, 64);
    sq += __shfl_down(sq, off, 64);
  }
  __shared__ float ws[16], wq[16];
  const int wv = tid >> 6;
  if ((tid & 63) == 0) { ws[wv] = s; wq[wv] = sq; }
  __syncthreads();
  if (tid == 0) {
    float S = 0.f, Q = 0.f;
    for (int i = 0; i < 16; i++) { S += ws[i]; Q += wq[i]; }
    const float mu = S / (float)(BB*NN);
    const float var = Q / (float)(BB*NN) - mu*mu;
    mean[c] = mu;
    istd[c] = rsqrtf(var + 1e-5f);
  }
}

// ---------------------------------------------------------------------------
// bnapply: out = relu((t-mean)*istd*g + b) [+ res]; handles strided batch dims
// ---------------------------------------------------------------------------
__global__ __launch_bounds__(256)
void bnapply_kernel(const float* __restrict__ t, const float* __restrict__ mean,
                    const float* __restrict__ istd, const float* __restrict__ g,
                    const float* __restrict__ bt,
                    const float* __restrict__ res, long resStride,
                    float* __restrict__ out, long outStride)
{
  const long total4 = (long)BB*CC*NN/4;
  for (long i4 = (long)blockIdx.x*256 + threadIdx.x; i4 < total4;
       i4 += (long)gridDim.x*256) {
    const long flat = i4*4;
    const int b = (int)(flat / ((long)CC*NN));
    const long rem = flat - (long)b*CC*NN;
    const int c = (int)(rem / NN);
    const float4 v = *(const float4*)&t[flat];
    const float mu = mean[c], is = istd[c], gg = g[c], bc = bt[c];
    float4 o;
    o.x = fmaxf((v.x - mu)*is*gg + bc, 0.f);
    o.y = fmaxf((v.y - mu)*is*gg + bc, 0.f);
    o.z = fmaxf((v.z - mu)*is*gg + bc, 0.f);
    o.w = fmaxf((v.w - mu)*is*gg + bc, 0.f);
    if (res) {
      const float4 rv = *(const float4*)&res[(long)b*resStride + rem];
      o.x += rv.x; o.y += rv.y; o.z += rv.z; o.w += rv.w;
    }
    *(float4*)&out[(long)b*outStride + rem] = o;
  }
}

// ---------------------------------------------------------------------------
extern "C" void kernel_launch(void* const* d_in, const int* in_sizes, int n_in,
                              void* d_out, int out_size, void* d_ws, size_t ws_size,
                              hipStream_t stream)
{
  const float* x_in   = (const float*)d_in[0];
  const int*   mask   = (const int*)d_in[1];
  const float* conv1w = (const float*)d_in[2];
  const float* conv2w = (const float*)d_in[3];
  const float* bn1g   = (const float*)d_in[4];
  const float* bn1b   = (const float*)d_in[5];
  const float* bn2g   = (const float*)d_in[6];
  const float* bn2b   = (const float*)d_in[7];
  const float* qkw    = (const float*)d_in[8];   // [4,H,C]
  const float* vw     = (const float*)d_in[9];   // [4,C,C]
  const float* vb     = (const float*)d_in[10];  // [4,C]
  const float* tw     = (const float*)d_in[11];  // [4,C,C]
  const float* tb     = (const float*)d_in[12];  // [4,C]
  const float* bng    = (const float*)d_in[13];  // [4,C]
  const float* bnb    = (const float*)d_in[14];  // [4,C]
  float* out = (float*)d_out;

  float* ws = (float*)d_ws;
  const long BCN = (long)BB*CC*NN;
  float* tbuf  = ws;
  float* xbuf  = tbuf  + BCN;
  float* qbuf  = xbuf  + BCN;
  float* xvbuf = qbuf  + (long)BB*HH*NN;
  float* ybuf  = xvbuf + BCN;
  float* rmaxb = ybuf  + (long)BB*(CC+1)*NN;
  float* rinvb = rmaxb + (long)BB*NN;
  float* meanb = rinvb + (long)BB*NN;
  float* istdb = meanb + CC;
  // total ws use: ~137 MiB

  const long CN  = (long)CC*NN;
  const long CN4 = 4*CN;
  const dim3 g256(NN/64, CC/64, BB);
  const dim3 g64 (NN/64, HH/64, BB);
  const dim3 gRow(NN/16, BB);
  const dim3 gAtt(NN/32, BB);

  // ---- pre-stage: conv1 -> bn -> relu -> conv2 -> bn -> relu ----
  gemm_wx<false><<<g256, 256, 0, stream>>>(conv1w, x_in, nullptr, nullptr, tbuf, CN, CN);
  bnstats_kernel<<<CC, 1024, 0, stream>>>(tbuf, meanb, istdb);
  bnapply_kernel<<<4096, 256, 0, stream>>>(tbuf, meanb, istdb, bn1g, bn1b,
                                           nullptr, 0, xbuf, CN);
  gemm_wx<false><<<g256, 256, 0, stream>>>(conv2w, xbuf, nullptr, nullptr, tbuf, CN, CN);
  bnstats_kernel<<<CC, 1024, 0, stream>>>(tbuf, meanb, istdb);
  bnapply_kernel<<<4096, 256, 0, stream>>>(tbuf, meanb, istdb, bn2g, bn2b,
                                           nullptr, 0, xbuf, CN);

  // ---- 4 SA layers; layer i writes its x into out slice i ----
  for (int i = 0; i < 4; i++) {
    const float* curx = (i == 0) ? xbuf : (out + (long)(i-1)*CN);
    const long   xs   = (i == 0) ? CN : CN4;

    gemm_wx<false><<<g64, 256, 0, stream>>>(qkw + (long)i*HH*CC, curx,
                                            nullptr, nullptr, qbuf, xs, (long)HH*NN);
    rowstat_kernel<<<gRow, 256, 0, stream>>>(qbuf, mask, rmaxb, rinvb);
    gemm_wx<false><<<g256, 256, 0, stream>>>(vw + (long)i*CC*CC, curx,
                                             vb + (long)i*CC, nullptr, xvbuf, xs, CN);
    yatt_kernel<<<gAtt, 256, 0, stream>>>(qbuf, xvbuf, mask, rmaxb, rinvb, ybuf);
    gemm_wx<true><<<g256, 256, 0, stream>>>(tw + (long)i*CC*CC, curx,
                                            tb + (long)i*CC, ybuf, tbuf, xs, CN);
    bnstats_kernel<<<CC, 1024, 0, stream>>>(tbuf, meanb, istdb);
    bnapply_kernel<<<4096, 256, 0, stream>>>(tbuf, meanb, istdb,
                                             bng + (long)i*CC, bnb + (long)i*CC,
                                             curx, xs, out + (long)i*CN, CN4);
  }

  (void)in_sizes; (void)n_in; (void)out_size; (void)ws_size;
}

// Round 5
// 954.817 us; speedup vs baseline: 13.4678x; 13.4678x over previous
//
#include <hip/hip_runtime.h>
#include <math.h>

#define BB 16
#define CC 256
#define NN 2048
#define HH 64
#define NEGV (-9.0e15f)
#define ATTSC 4096.0f
#define ATTINV (1.0f/4096.0f)

typedef _Float16 f16x8 __attribute__((ext_vector_type(8)));
typedef float f32x4 __attribute__((ext_vector_type(4)));

__device__ __forceinline__ f32x4 mfma16(f16x8 a, f16x8 b, f32x4 c) {
  return __builtin_amdgcn_mfma_f32_16x16x32_f16(a, b, c, 0, 0, 0);
}
__device__ __forceinline__ unsigned short f2h(float f) {
  _Float16 h = (_Float16)f;
  return __builtin_bit_cast(unsigned short, h);
}
__device__ __forceinline__ float h2f(unsigned short u) {
  return (float)__builtin_bit_cast(_Float16, u);
}

// ---------------------------------------------------------------------------
// weight cast fp32 -> fp16
// ---------------------------------------------------------------------------
__global__ __launch_bounds__(256)
void castw_kernel(const float* __restrict__ in, unsigned short* __restrict__ out, int n)
{
  const int i = blockIdx.x*256 + threadIdx.x;
  if (i < n) out[i] = f2h(in[i]);
}

// ---------------------------------------------------------------------------
// transpose-cast: src fp32 [b][C][N] (batch stride sstride) -> dst f16 [B][N][C]
// ---------------------------------------------------------------------------
__global__ __launch_bounds__(256)
void tcast_kernel(const float* __restrict__ src, long sstride,
                  unsigned short* __restrict__ dst)
{
  const int b = blockIdx.z, n0 = blockIdx.x*64, c0 = blockIdx.y*64;
  const int t = threadIdx.x;
  __shared__ float tile[64][66];   // [c][n]
  const float* sb = src + (long)b*sstride;
  #pragma unroll
  for (int p = 0; p < 4; p++) {
    const int cr = (t>>4) + p*16;
    const int nq = (t&15)*4;
    const float4 v = *(const float4*)&sb[(long)(c0+cr)*NN + n0 + nq];
    tile[cr][nq+0] = v.x; tile[cr][nq+1] = v.y;
    tile[cr][nq+2] = v.z; tile[cr][nq+3] = v.w;
  }
  __syncthreads();
  unsigned short* db = dst + (long)b*NN*CC;
  #pragma unroll
  for (int p = 0; p < 4; p++) {
    const int nr = (t>>4) + p*16;
    const int cq = (t&15)*4;
    ushort4 o;
    o.x = f2h(tile[cq+0][nr]); o.y = f2h(tile[cq+1][nr]);
    o.z = f2h(tile[cq+2][nr]); o.w = f2h(tile[cq+3][nr]);
    *(ushort4*)&db[(long)(n0+nr)*CC + c0 + cq] = o;
  }
}

// ---------------------------------------------------------------------------
// GEMM (A-major n): D[n][o] = sum_c A[n][c] * W[o][c] (+bias[o])
// A f16 [B][N][CC], W f16 [O][CC]. 64x64 tile, 4 waves, MFMA 16x16x32.
// ---------------------------------------------------------------------------
template<bool OHALF>
__global__ __launch_bounds__(256)
void gemm_xw_kernel(const unsigned short* __restrict__ A,
                    const unsigned short* __restrict__ W,
                    const float* __restrict__ bias,
                    void* __restrict__ out, int ocols)
{
  const int n0 = blockIdx.x*64, o0 = blockIdx.y*64, b = blockIdx.z;
  const int t = threadIdx.x;
  const int w = t >> 6, l = t & 63, lr = l & 15, lg = l >> 4;
  const int wr = w >> 1, wc = w & 1;
  __shared__ unsigned short Al[64][72];
  __shared__ unsigned short Bl[64][72];
  const unsigned short* Ab = A + ((long)b*NN + n0)*CC;
  const int srow = t >> 3, sg = t & 7;
  f32x4 acc[2][2];
  #pragma unroll
  for (int i = 0; i < 2; i++)
    #pragma unroll
    for (int j = 0; j < 2; j++) acc[i][j] = f32x4{0.f,0.f,0.f,0.f};

  for (int kt = 0; kt < 4; kt++) {
    const int k0 = kt*64;
    const uint4 a0 = *(const uint4*)&Ab[(long)srow*CC + k0 + sg*8];
    const uint4 a1 = *(const uint4*)&Ab[(long)(srow+32)*CC + k0 + sg*8];
    const uint4 w0 = *(const uint4*)&W[(long)(o0+srow)*CC + k0 + sg*8];
    const uint4 w1 = *(const uint4*)&W[(long)(o0+srow+32)*CC + k0 + sg*8];
    __syncthreads();
    *(uint4*)&Al[srow][sg*8] = a0;  *(uint4*)&Al[srow+32][sg*8] = a1;
    *(uint4*)&Bl[srow][sg*8] = w0;  *(uint4*)&Bl[srow+32][sg*8] = w1;
    __syncthreads();
    #pragma unroll
    for (int kf = 0; kf < 2; kf++) {
      f16x8 af0 = *(const f16x8*)&Al[wr*32 + lr]     [kf*32 + lg*8];
      f16x8 af1 = *(const f16x8*)&Al[wr*32 + 16 + lr][kf*32 + lg*8];
      f16x8 bf0 = *(const f16x8*)&Bl[wc*32 + lr]     [kf*32 + lg*8];
      f16x8 bf1 = *(const f16x8*)&Bl[wc*32 + 16 + lr][kf*32 + lg*8];
      acc[0][0] = mfma16(af0, bf0, acc[0][0]);
      acc[0][1] = mfma16(af0, bf1, acc[0][1]);
      acc[1][0] = mfma16(af1, bf0, acc[1][0]);
      acc[1][1] = mfma16(af1, bf1, acc[1][1]);
    }
  }
  #pragma unroll
  for (int j = 0; j < 2; j++) {
    const int oc = o0 + wc*32 + j*16 + lr;
    const float bo = bias ? bias[oc] : 0.f;
    #pragma unroll
    for (int i = 0; i < 2; i++) {
      const int nb = n0 + wr*32 + i*16 + lg*4;
      #pragma unroll
      for (int r = 0; r < 4; r++) {
        const float v = acc[i][j][r] + bo;
        const long idx = ((long)b*NN + nb + r)*ocols + oc;
        if (OHALF) ((unsigned short*)out)[idx] = f2h(v);
        else       ((float*)out)[idx] = v;
      }
    }
  }
}

// ---------------------------------------------------------------------------
// GEMM (W-major o): out[o][n] = sum_c W[o][c] * X[n][c] + bias[o]; out f16 [B][CC][NN]
// ---------------------------------------------------------------------------
__global__ __launch_bounds__(256)
void gemm_wx_kernel(const unsigned short* __restrict__ W,
                    const unsigned short* __restrict__ X,
                    const float* __restrict__ bias,
                    unsigned short* __restrict__ out)
{
  const int n0 = blockIdx.x*64, o0 = blockIdx.y*64, b = blockIdx.z;
  const int t = threadIdx.x;
  const int w = t >> 6, l = t & 63, lr = l & 15, lg = l >> 4;
  const int wr = w >> 1, wc = w & 1;
  __shared__ unsigned short Al[64][72];
  __shared__ unsigned short Bl[64][72];
  const unsigned short* Xb = X + ((long)b*NN + n0)*CC;
  const int srow = t >> 3, sg = t & 7;
  f32x4 acc[2][2];
  #pragma unroll
  for (int i = 0; i < 2; i++)
    #pragma unroll
    for (int j = 0; j < 2; j++) acc[i][j] = f32x4{0.f,0.f,0.f,0.f};

  for (int kt = 0; kt < 4; kt++) {
    const int k0 = kt*64;
    const uint4 w0 = *(const uint4*)&W[(long)(o0+srow)*CC + k0 + sg*8];
    const uint4 w1 = *(const uint4*)&W[(long)(o0+srow+32)*CC + k0 + sg*8];
    const uint4 x0 = *(const uint4*)&Xb[(long)srow*CC + k0 + sg*8];
    const uint4 x1 = *(const uint4*)&Xb[(long)(srow+32)*CC + k0 + sg*8];
    __syncthreads();
    *(uint4*)&Al[srow][sg*8] = w0;  *(uint4*)&Al[srow+32][sg*8] = w1;
    *(uint4*)&Bl[srow][sg*8] = x0;  *(uint4*)&Bl[srow+32][sg*8] = x1;
    __syncthreads();
    #pragma unroll
    for (int kf = 0; kf < 2; kf++) {
      f16x8 af0 = *(const f16x8*)&Al[wr*32 + lr]     [kf*32 + lg*8];
      f16x8 af1 = *(const f16x8*)&Al[wr*32 + 16 + lr][kf*32 + lg*8];
      f16x8 bf0 = *(const f16x8*)&Bl[wc*32 + lr]     [kf*32 + lg*8];
      f16x8 bf1 = *(const f16x8*)&Bl[wc*32 + 16 + lr][kf*32 + lg*8];
      acc[0][0] = mfma16(af0, bf0, acc[0][0]);
      acc[0][1] = mfma16(af0, bf1, acc[0][1]);
      acc[1][0] = mfma16(af1, bf0, acc[1][0]);
      acc[1][1] = mfma16(af1, bf1, acc[1][1]);
    }
  }
  #pragma unroll
  for (int j = 0; j < 2; j++) {
    const int nc = n0 + wc*32 + j*16 + lr;
    #pragma unroll
    for (int i = 0; i < 2; i++) {
      #pragma unroll
      for (int r = 0; r < 4; r++) {
        const int oc = o0 + wr*32 + i*16 + lg*4 + r;
        out[((long)b*CC + oc)*NN + nc] = f2h(acc[i][j][r] + bias[oc]);
      }
    }
  }
}

// ---------------------------------------------------------------------------
// rowstat: per (b,n): max_m and 1/sum_m of exp(masked S[n,m]); S via MFMA.
// ---------------------------------------------------------------------------
__global__ __launch_bounds__(256)
void rowstat_kernel(const unsigned short* __restrict__ qT, const int* __restrict__ mask,
                    float* __restrict__ rmax, float* __restrict__ rinv)
{
  const int b = blockIdx.y, n0 = blockIdx.x*64;
  const int t = threadIdx.x, w = t>>6, l = t&63, lr = l&15, lg = l>>4;
  __shared__ unsigned short qa[64][72];
  __shared__ unsigned short qb[64][72];
  __shared__ int ml[64];
  const int srow = t>>3, sg = t&7;
  const unsigned short* qbase = qT + (long)b*NN*HH;
  *(uint4*)&qa[srow][sg*8]    = *(const uint4*)&qbase[(long)(n0+srow)*HH + sg*8];
  *(uint4*)&qa[srow+32][sg*8] = *(const uint4*)&qbase[(long)(n0+srow+32)*HH + sg*8];
  int maskn[4];
  #pragma unroll
  for (int r = 0; r < 4; r++) maskn[r] = mask[(long)b*NN + n0 + w*16 + lg*4 + r];
  __syncthreads();
  f16x8 af0 = *(const f16x8*)&qa[w*16 + lr][lg*8];
  f16x8 af1 = *(const f16x8*)&qa[w*16 + lr][32 + lg*8];
  float mx[4], sm[4];
  #pragma unroll
  for (int r = 0; r < 4; r++) { mx[r] = -INFINITY; sm[r] = 0.f; }

  for (int m0 = 0; m0 < NN; m0 += 64) {
    __syncthreads();
    *(uint4*)&qb[srow][sg*8]    = *(const uint4*)&qbase[(long)(m0+srow)*HH + sg*8];
    *(uint4*)&qb[srow+32][sg*8] = *(const uint4*)&qbase[(long)(m0+srow+32)*HH + sg*8];
    if (t < 64) ml[t] = mask[(long)b*NN + m0 + t];
    __syncthreads();
    #pragma unroll
    for (int tm = 0; tm < 4; tm++) {
      f32x4 s = f32x4{0.f,0.f,0.f,0.f};
      s = mfma16(af0, *(const f16x8*)&qb[tm*16 + lr][lg*8],      s);
      s = mfma16(af1, *(const f16x8*)&qb[tm*16 + lr][32 + lg*8], s);
      const int cm = ml[tm*16 + lr];
      #pragma unroll
      for (int r = 0; r < 4; r++) {
        const float vm = (maskn[r] && cm) ? s[r] : NEGV;
        const float nm = fmaxf(mx[r], vm);
        sm[r] = sm[r]*__expf(mx[r]-nm) + __expf(vm-nm);
        mx[r] = nm;
      }
    }
  }
  #pragma unroll
  for (int off = 1; off < 16; off <<= 1) {
    #pragma unroll
    for (int r = 0; r < 4; r++) {
      const float om = __shfl_xor(mx[r], off, 64);
      const float os = __shfl_xor(sm[r], off, 64);
      const float nm = fmaxf(mx[r], om);
      sm[r] = sm[r]*__expf(mx[r]-nm) + os*__expf(om-nm);
      mx[r] = nm;
    }
  }
  if (lr == 0) {
    #pragma unroll
    for (int r = 0; r < 4; r++) {
      const long idx = (long)b*NN + n0 + w*16 + lg*4 + r;
      rmax[idx] = mx[r];
      rinv[idx] = 1.f/sm[r];
    }
  }
}

// ---------------------------------------------------------------------------
// yatt: x_rT[m][c] = sum_n xv[c][n]*Atil[n][m]; csum[m] = sum_n Atil[n][m].
// Atil recomputed from qT tiles via MFMA, exp in fp32, stored f16*4096 in LDS
// (pre-scale keeps small attention weights out of the f16 denormal zone).
// ---------------------------------------------------------------------------
__global__ __launch_bounds__(256)
void yatt_kernel(const unsigned short* __restrict__ qT, const unsigned short* __restrict__ xv,
                 const int* __restrict__ mask, const float* __restrict__ rmax,
                 const float* __restrict__ rinv, float* __restrict__ xrT,
                 float* __restrict__ csum)
{
  const int b = blockIdx.y, m0 = blockIdx.x*64;
  const int t = threadIdx.x, w = t>>6, l = t&63, lr = l&15, lg = l>>4;
  __shared__ unsigned short qm[64][72];
  __shared__ unsigned short qn[64][72];
  __shared__ unsigned short at[64][72];
  __shared__ unsigned short xvl[256][72];
  __shared__ float rml[64], ril[64];
  __shared__ int mrl[64];
  const int srow = t>>3, sg = t&7;
  const unsigned short* qbase = qT + (long)b*NN*HH;
  const unsigned short* xvb = xv + (long)b*CC*NN;
  *(uint4*)&qm[srow][sg*8]    = *(const uint4*)&qbase[(long)(m0+srow)*HH + sg*8];
  *(uint4*)&qm[srow+32][sg*8] = *(const uint4*)&qbase[(long)(m0+srow+32)*HH + sg*8];
  int maskm[4];
  #pragma unroll
  for (int r = 0; r < 4; r++) maskm[r] = mask[(long)b*NN + m0 + w*16 + lg*4 + r];
  __syncthreads();
  f16x8 am0 = *(const f16x8*)&qm[w*16 + lr][lg*8];
  f16x8 am1 = *(const f16x8*)&qm[w*16 + lr][32 + lg*8];
  f32x4 acc[16];
  #pragma unroll
  for (int ct = 0; ct < 16; ct++) acc[ct] = f32x4{0.f,0.f,0.f,0.f};
  float cs[4] = {0.f, 0.f, 0.f, 0.f};

  for (int nc = 0; nc < NN; nc += 64) {
    __syncthreads();
    *(uint4*)&qn[srow][sg*8]    = *(const uint4*)&qbase[(long)(nc+srow)*HH + sg*8];
    *(uint4*)&qn[srow+32][sg*8] = *(const uint4*)&qbase[(long)(nc+srow+32)*HH + sg*8];
    if (t < 64) {
      rml[t] = rmax[(long)b*NN + nc + t];
      ril[t] = rinv[(long)b*NN + nc + t];
      mrl[t] = mask[(long)b*NN + nc + t];
    }
    #pragma unroll
    for (int i2 = 0; i2 < 8; i2++) {
      const int c = i2*32 + (t>>3);
      *(uint4*)&xvl[c][sg*8] = *(const uint4*)&xvb[(long)c*NN + nc + sg*8];
    }
    __syncthreads();
    // S phase: D[m][n] = energy (symmetric), exp -> at[m][n] f16 (scaled)
    #pragma unroll
    for (int tn = 0; tn < 4; tn++) {
      f32x4 s = f32x4{0.f,0.f,0.f,0.f};
      s = mfma16(am0, *(const f16x8*)&qn[tn*16 + lr][lg*8],      s);
      s = mfma16(am1, *(const f16x8*)&qn[tn*16 + lr][32 + lg*8], s);
      const int nn = tn*16 + lr;
      const int cm = mrl[nn];
      const float rm = rml[nn], ri = ril[nn];
      #pragma unroll
      for (int r = 0; r < 4; r++) {
        const float vm = (maskm[r] && cm) ? s[r] : NEGV;
        const float a_ = __expf(vm - rm) * ri;
        cs[r] += a_;
        at[w*16 + lg*4 + r][nn] = f2h(a_ * ATTSC);
      }
    }
    // PV phase: acc[m][c] += at[m][n'] * xvl[c][n']
    f16x8 aat0 = *(const f16x8*)&at[w*16 + lr][lg*8];
    f16x8 aat1 = *(const f16x8*)&at[w*16 + lr][32 + lg*8];
    #pragma unroll
    for (int ct = 0; ct < 16; ct++) {
      acc[ct] = mfma16(aat0, *(const f16x8*)&xvl[ct*16 + lr][lg*8],      acc[ct]);
      acc[ct] = mfma16(aat1, *(const f16x8*)&xvl[ct*16 + lr][32 + lg*8], acc[ct]);
    }
  }
  #pragma unroll
  for (int ct = 0; ct < 16; ct++) {
    #pragma unroll
    for (int r = 0; r < 4; r++)
      xrT[((long)b*NN + m0 + w*16 + lg*4 + r)*CC + ct*16 + lr] = acc[ct][r] * ATTINV;
  }
  #pragma unroll
  for (int off = 1; off < 16; off <<= 1) {
    #pragma unroll
    for (int r = 0; r < 4; r++) cs[r] += __shfl_xor(cs[r], off, 64);
  }
  if (lr == 0) {
    #pragma unroll
    for (int r = 0; r < 4; r++)
      csum[(long)b*NN + m0 + w*16 + lg*4 + r] = cs[r];
  }
}

// ---------------------------------------------------------------------------
// diff: dT[p][c] = f16( xT[p][c] - xrT[p][c]/(1e-9 + csum[p]) )
// ---------------------------------------------------------------------------
__global__ __launch_bounds__(256)
void diff_kernel(const unsigned short* __restrict__ xT, const float* __restrict__ xrT,
                 const float* __restrict__ csumv, unsigned short* __restrict__ dT)
{
  const long i = (long)blockIdx.x*256 + threadIdx.x;
  const long base = i*8;
  const long row = base >> 8;
  const float inv = 1.f/(1e-9f + csumv[row]);
  const uint4 xu = *(const uint4*)&xT[base];
  const float4 y0 = *(const float4*)&xrT[base];
  const float4 y1 = *(const float4*)&xrT[base+4];
  const unsigned short* xs = (const unsigned short*)&xu;
  ushort4 o0, o1;
  o0.x = f2h(h2f(xs[0]) - y0.x*inv);
  o0.y = f2h(h2f(xs[1]) - y0.y*inv);
  o0.z = f2h(h2f(xs[2]) - y0.z*inv);
  o0.w = f2h(h2f(xs[3]) - y0.w*inv);
  o1.x = f2h(h2f(xs[4]) - y1.x*inv);
  o1.y = f2h(h2f(xs[5]) - y1.y*inv);
  o1.z = f2h(h2f(xs[6]) - y1.z*inv);
  o1.w = f2h(h2f(xs[7]) - y1.w*inv);
  *(ushort4*)&dT[base]   = o0;
  *(ushort4*)&dT[base+4] = o1;
}

// ---------------------------------------------------------------------------
// BN stats, two-stage deterministic over [B*N][C]
// ---------------------------------------------------------------------------
__global__ __launch_bounds__(256)
void bnstatsA_kernel(const float* __restrict__ tT, float* __restrict__ part)
{
  const int k = blockIdx.x;      // 256 blocks x 128 rows
  const int c = threadIdx.x;
  float s = 0.f, sq = 0.f;
  const long r0 = (long)k*128;
  for (int r = 0; r < 128; r++) {
    const float v = tT[(r0 + r)*CC + c];
    s += v; sq += v*v;
  }
  part[(long)k*CC + c] = s;
  part[(long)(256 + k)*CC + c] = sq;
}

__global__ __launch_bounds__(1024)
void bnstatsB_kernel(const float* __restrict__ part,
                     float* __restrict__ mean, float* __restrict__ istd)
{
  const int t = threadIdx.x, c = t & 255, q = t >> 8;
  float s = 0.f, sq = 0.f;
  for (int k = q*64; k < q*64 + 64; k++) {
    s  += part[(long)k*CC + c];
    sq += part[(long)(256 + k)*CC + c];
  }
  __shared__ float ls[4][256], lq[4][256];
  ls[q][c] = s; lq[q][c] = sq;
  __syncthreads();
  if (q == 0) {
    s  = ls[0][c] + ls[1][c] + ls[2][c] + ls[3][c];
    sq = lq[0][c] + lq[1][c] + lq[2][c] + lq[3][c];
    const float mu = s / (float)(BB*NN);
    mean[c] = mu;
    istd[c] = rsqrtf(sq/(float)(BB*NN) - mu*mu + 1e-5f);
  }
}

// ---------------------------------------------------------------------------
// bnapplyA: xTo[p][c] = f16(relu(bn(tT[p][c])))  (elementwise, [N][C] layout)
// ---------------------------------------------------------------------------
__global__ __launch_bounds__(256)
void bnapplyA_kernel(const float* __restrict__ tT, const float* __restrict__ mean,
                     const float* __restrict__ istd, const float* __restrict__ g,
                     const float* __restrict__ bt, unsigned short* __restrict__ xTo)
{
  __shared__ float sc[CC], sh[CC];
  const int t = threadIdx.x;
  {
    const float is = istd[t], gg = g[t];
    sc[t] = is*gg; sh[t] = bt[t] - mean[t]*is*gg;
  }
  __syncthreads();
  const long i = (long)blockIdx.x*256 + t;
  const long base = i*8;
  const int c8 = (int)(base & 255);
  const float4 v0 = *(const float4*)&tT[base];
  const float4 v1 = *(const float4*)&tT[base+4];
  ushort4 o0, o1;
  o0.x = f2h(fmaxf(v0.x*sc[c8+0] + sh[c8+0], 0.f));
  o0.y = f2h(fmaxf(v0.y*sc[c8+1] + sh[c8+1], 0.f));
  o0.z = f2h(fmaxf(v0.z*sc[c8+2] + sh[c8+2], 0.f));
  o0.w = f2h(fmaxf(v0.w*sc[c8+3] + sh[c8+3], 0.f));
  o1.x = f2h(fmaxf(v1.x*sc[c8+4] + sh[c8+4], 0.f));
  o1.y = f2h(fmaxf(v1.y*sc[c8+5] + sh[c8+5], 0.f));
  o1.z = f2h(fmaxf(v1.z*sc[c8+6] + sh[c8+6], 0.f));
  o1.w = f2h(fmaxf(v1.w*sc[c8+7] + sh[c8+7], 0.f));
  *(ushort4*)&xTo[base]   = o0;
  *(ushort4*)&xTo[base+4] = o1;
}

// ---------------------------------------------------------------------------
// bnapplyT: outp[c][n] = relu(bn(tT[n][c])) [+ resid[c][n]]  (LDS transpose)
// ---------------------------------------------------------------------------
__global__ __launch_bounds__(256)
void bnapplyT_kernel(const float* __restrict__ tT, const float* __restrict__ mean,
                     const float* __restrict__ istd, const float* __restrict__ g,
                     const float* __restrict__ bt, const float* __restrict__ resid,
                     long rstride, float* __restrict__ outp, long ostride)
{
  const int b = blockIdx.z, n0 = blockIdx.x*64, c0 = blockIdx.y*64;
  const int t = threadIdx.x;
  __shared__ float tile[64][66];   // [c][n]
  const float* tb_ = tT + ((long)b*NN + n0)*CC;
  const int cq = (t&15)*4;
  float scv[4], shv[4];
  #pragma unroll
  for (int j = 0; j < 4; j++) {
    const int c = c0 + cq + j;
    const float is = istd[c], gg = g[c];
    scv[j] = is*gg; shv[j] = bt[c] - mean[c]*is*gg;
  }
  #pragma unroll
  for (int p = 0; p < 4; p++) {
    const int nr = (t>>4) + p*16;
    const float4 v = *(const float4*)&tb_[(long)nr*CC + c0 + cq];
    tile[cq+0][nr] = fmaxf(v.x*scv[0] + shv[0], 0.f);
    tile[cq+1][nr] = fmaxf(v.y*scv[1] + shv[1], 0.f);
    tile[cq+2][nr] = fmaxf(v.z*scv[2] + shv[2], 0.f);
    tile[cq+3][nr] = fmaxf(v.w*scv[3] + shv[3], 0.f);
  }
  __syncthreads();
  const int nq = (t&15)*4;
  #pragma unroll
  for (int p = 0; p < 4; p++) {
    const int cr = (t>>4) + p*16;
    float4 o;
    o.x = tile[cr][nq+0]; o.y = tile[cr][nq+1];
    o.z = tile[cr][nq+2]; o.w = tile[cr][nq+3];
    if (resid) {
      const float4 rv = *(const float4*)&resid[(long)b*rstride + (long)(c0+cr)*NN + n0 + nq];
      o.x += rv.x; o.y += rv.y; o.z += rv.z; o.w += rv.w;
    }
    *(float4*)&outp[(long)b*ostride + (long)(c0+cr)*NN + n0 + nq] = o;
  }
}

// ---------------------------------------------------------------------------
extern "C" void kernel_launch(void* const* d_in, const int* in_sizes, int n_in,
                              void* d_out, int out_size, void* d_ws, size_t ws_size,
                              hipStream_t stream)
{
  const float* x_in   = (const float*)d_in[0];
  const int*   mask   = (const int*)d_in[1];
  const float* conv1w = (const float*)d_in[2];
  const float* conv2w = (const float*)d_in[3];
  const float* bn1g   = (const float*)d_in[4];
  const float* bn1b   = (const float*)d_in[5];
  const float* bn2g   = (const float*)d_in[6];
  const float* bn2b   = (const float*)d_in[7];
  const float* qkw    = (const float*)d_in[8];
  const float* vw     = (const float*)d_in[9];
  const float* vb     = (const float*)d_in[10];
  const float* tw     = (const float*)d_in[11];
  const float* tb     = (const float*)d_in[12];
  const float* bng    = (const float*)d_in[13];
  const float* bnb    = (const float*)d_in[14];
  float* out = (float*)d_out;

  const long BCN = (long)BB*CC*NN;
  const long CN  = (long)CC*NN;
  char* p = (char*)d_ws;
  unsigned short* xTa = (unsigned short*)p; p += BCN*2;
  unsigned short* xTb = (unsigned short*)p; p += BCN*2;
  unsigned short* qTb = (unsigned short*)p; p += (long)BB*NN*HH*2;
  unsigned short* xvb = (unsigned short*)p; p += BCN*2;   // aliased as dT
  float* tT    = (float*)p; p += BCN*4;                   // aliased as xrT
  float* xbuf  = (float*)p; p += BCN*4;
  float* rmaxb = (float*)p; p += (long)BB*NN*4;
  float* rinvb = (float*)p; p += (long)BB*NN*4;
  float* csumb = (float*)p; p += (long)BB*NN*4;
  float* partb = (float*)p; p += 512L*CC*4;
  float* meanb = (float*)p; p += CC*4;
  float* istdb = (float*)p; p += CC*4;
  unsigned short* wc1 = (unsigned short*)p; p += (long)CC*CC*2;
  unsigned short* wc2 = (unsigned short*)p; p += (long)CC*CC*2;
  unsigned short* wqk = (unsigned short*)p; p += 4L*HH*CC*2;
  unsigned short* wv  = (unsigned short*)p; p += 4L*CC*CC*2;
  unsigned short* wt  = (unsigned short*)p; p += 4L*CC*CC*2;

  const dim3 gT(NN/64, CC/64, BB);      // 32,4,16
  const dim3 gQ(NN/64, 1, BB);          // qk gemm (O=64)
  const dim3 gRS(NN/64, BB);
  const dim3 blk(256);

  // weight casts
  castw_kernel<<<dim3(256), blk, 0, stream>>>(conv1w, wc1, CC*CC);
  castw_kernel<<<dim3(256), blk, 0, stream>>>(conv2w, wc2, CC*CC);
  castw_kernel<<<dim3(256), blk, 0, stream>>>(qkw, wqk, 4*HH*CC);
  castw_kernel<<<dim3(1024), blk, 0, stream>>>(vw, wv, 4*CC*CC);
  castw_kernel<<<dim3(1024), blk, 0, stream>>>(tw, wt, 4*CC*CC);

  // pre-stage
  tcast_kernel<<<gT, blk, 0, stream>>>(x_in, CN, xTa);
  gemm_xw_kernel<false><<<gT, blk, 0, stream>>>(xTa, wc1, nullptr, tT, CC);
  bnstatsA_kernel<<<dim3(256), blk, 0, stream>>>(tT, partb);
  bnstatsB_kernel<<<dim3(1), dim3(1024), 0, stream>>>(partb, meanb, istdb);
  bnapplyA_kernel<<<dim3(4096), blk, 0, stream>>>(tT, meanb, istdb, bn1g, bn1b, xTb);
  gemm_xw_kernel<false><<<gT, blk, 0, stream>>>(xTb, wc2, nullptr, tT, CC);
  bnstatsA_kernel<<<dim3(256), blk, 0, stream>>>(tT, partb);
  bnstatsB_kernel<<<dim3(1), dim3(1024), 0, stream>>>(partb, meanb, istdb);
  bnapplyT_kernel<<<gT, blk, 0, stream>>>(tT, meanb, istdb, bn2g, bn2b,
                                          nullptr, 0, xbuf, CN);
  tcast_kernel<<<gT, blk, 0, stream>>>(xbuf, CN, xTa);

  unsigned short* cur = xTa;
  unsigned short* nxt = xTb;
  for (int i = 0; i < 4; i++) {
    gemm_xw_kernel<true><<<gQ, blk, 0, stream>>>(cur, wqk + (long)i*HH*CC, nullptr, qTb, HH);
    rowstat_kernel<<<gRS, blk, 0, stream>>>(qTb, mask, rmaxb, rinvb);
    gemm_wx_kernel<<<gT, blk, 0, stream>>>(wv + (long)i*CC*CC, cur, vb + (long)i*CC, xvb);
    yatt_kernel<<<gRS, blk, 0, stream>>>(qTb, xvb, mask, rmaxb, rinvb, tT, csumb);
    diff_kernel<<<dim3(4096), blk, 0, stream>>>(cur, tT, csumb, xvb);
    gemm_xw_kernel<false><<<gT, blk, 0, stream>>>(xvb, wt + (long)i*CC*CC, tb + (long)i*CC, tT, CC);
    bnstatsA_kernel<<<dim3(256), blk, 0, stream>>>(tT, partb);
    bnstatsB_kernel<<<dim3(1), dim3(1024), 0, stream>>>(partb, meanb, istdb);
    const float* resid = (i == 0) ? xbuf : (out + (long)(i-1)*CN);
    const long rstr = (i == 0) ? CN : 4*CN;
    bnapplyT_kernel<<<gT, blk, 0, stream>>>(tT, meanb, istdb,
                                            bng + (long)i*CC, bnb + (long)i*CC,
                                            resid, rstr, out + (long)i*CN, 4*CN);
    if (i < 3)
      tcast_kernel<<<gT, blk, 0, stream>>>(out + (long)i*CN, 4*CN, nxt);
    unsigned short* tmp = cur; cur = nxt; nxt = tmp;
  }

  (void)in_sizes; (void)n_in; (void)out_size; (void)ws_size;
}

// Round 6
// 773.288 us; speedup vs baseline: 16.6294x; 1.2348x over previous
//
#include <hip/hip_runtime.h>
#include <math.h>

#define BB 16
#define CC 256
#define NN 2048
#define HH 64
#define NEGV (-9.0e15f)
#define ATTSC 4096.0f
#define ATTINV (1.0f/4096.0f)

typedef _Float16 f16x8 __attribute__((ext_vector_type(8)));
typedef float f32x4 __attribute__((ext_vector_type(4)));

__device__ __forceinline__ f32x4 mfma16(f16x8 a, f16x8 b, f32x4 c) {
  return __builtin_amdgcn_mfma_f32_16x16x32_f16(a, b, c, 0, 0, 0);
}
__device__ __forceinline__ unsigned short f2h(float f) {
  _Float16 h = (_Float16)f;
  return __builtin_bit_cast(unsigned short, h);
}
__device__ __forceinline__ float h2f(unsigned short u) {
  return (float)__builtin_bit_cast(_Float16, u);
}
// Swizzled LDS tile accessor: row-major [R][64] f16, 128B rows,
// byte ^= ((row&7)<<4) spreads same-column b128 reads across banks (T2).
__device__ __forceinline__ unsigned short* sp(unsigned short* base, int row, int colh) {
  return (unsigned short*)((char*)base + (row << 7) + (((colh << 1)) ^ ((row & 7) << 4)));
}
__device__ __forceinline__ const unsigned short* spc(const unsigned short* base, int row, int colh) {
  return (const unsigned short*)((const char*)base + (row << 7) + (((colh << 1)) ^ ((row & 7) << 4)));
}

// ---------------------------------------------------------------------------
// weight cast fp32 -> fp16
// ---------------------------------------------------------------------------
__global__ __launch_bounds__(256)
void castw_kernel(const float* __restrict__ in, unsigned short* __restrict__ out, int n)
{
  const int i = blockIdx.x*256 + threadIdx.x;
  if (i < n) out[i] = f2h(in[i]);
}

// ---------------------------------------------------------------------------
// transpose-cast: src fp32 [b][C][N] -> dst f16 [B][N][C]  (input stage only)
// ---------------------------------------------------------------------------
__global__ __launch_bounds__(256)
void tcast_kernel(const float* __restrict__ src, long sstride,
                  unsigned short* __restrict__ dst)
{
  const int b = blockIdx.z, n0 = blockIdx.x*64, c0 = blockIdx.y*64;
  const int t = threadIdx.x;
  __shared__ float tile[64][66];   // [c][n]
  const float* sb = src + (long)b*sstride;
  #pragma unroll
  for (int p = 0; p < 4; p++) {
    const int cr = (t>>4) + p*16;
    const int nq = (t&15)*4;
    const float4 v = *(const float4*)&sb[(long)(c0+cr)*NN + n0 + nq];
    tile[cr][nq+0] = v.x; tile[cr][nq+1] = v.y;
    tile[cr][nq+2] = v.z; tile[cr][nq+3] = v.w;
  }
  __syncthreads();
  unsigned short* db = dst + (long)b*NN*CC;
  #pragma unroll
  for (int p = 0; p < 4; p++) {
    const int nr = (t>>4) + p*16;
    const int cq = (t&15)*4;
    ushort4 o;
    o.x = f2h(tile[cq+0][nr]); o.y = f2h(tile[cq+1][nr]);
    o.z = f2h(tile[cq+2][nr]); o.w = f2h(tile[cq+3][nr]);
    *(ushort4*)&db[(long)(n0+nr)*CC + c0 + cq] = o;
  }
}

// ---------------------------------------------------------------------------
// GEMM (A-major n): D[n][o] = sum_c A[n][c] * W[o][c] (+bias[o]); out f16
// ---------------------------------------------------------------------------
__global__ __launch_bounds__(256)
void gemm_xw_kernel(const unsigned short* __restrict__ A,
                    const unsigned short* __restrict__ W,
                    const float* __restrict__ bias,
                    unsigned short* __restrict__ out, int ocols)
{
  const int n0 = blockIdx.x*64, o0 = blockIdx.y*64, b = blockIdx.z;
  const int t = threadIdx.x;
  const int w = t >> 6, l = t & 63, lr = l & 15, lg = l >> 4;
  const int wr = w >> 1, wc = w & 1;
  __shared__ unsigned short Al[64][72];
  __shared__ unsigned short Bl[64][72];
  const unsigned short* Ab = A + ((long)b*NN + n0)*CC;
  const int srow = t >> 3, sg = t & 7;
  f32x4 acc[2][2];
  #pragma unroll
  for (int i = 0; i < 2; i++)
    #pragma unroll
    for (int j = 0; j < 2; j++) acc[i][j] = f32x4{0.f,0.f,0.f,0.f};

  for (int kt = 0; kt < 4; kt++) {
    const int k0 = kt*64;
    const uint4 a0 = *(const uint4*)&Ab[(long)srow*CC + k0 + sg*8];
    const uint4 a1 = *(const uint4*)&Ab[(long)(srow+32)*CC + k0 + sg*8];
    const uint4 w0 = *(const uint4*)&W[(long)(o0+srow)*CC + k0 + sg*8];
    const uint4 w1 = *(const uint4*)&W[(long)(o0+srow+32)*CC + k0 + sg*8];
    __syncthreads();
    *(uint4*)&Al[srow][sg*8] = a0;  *(uint4*)&Al[srow+32][sg*8] = a1;
    *(uint4*)&Bl[srow][sg*8] = w0;  *(uint4*)&Bl[srow+32][sg*8] = w1;
    __syncthreads();
    #pragma unroll
    for (int kf = 0; kf < 2; kf++) {
      f16x8 af0 = *(const f16x8*)&Al[wr*32 + lr]     [kf*32 + lg*8];
      f16x8 af1 = *(const f16x8*)&Al[wr*32 + 16 + lr][kf*32 + lg*8];
      f16x8 bf0 = *(const f16x8*)&Bl[wc*32 + lr]     [kf*32 + lg*8];
      f16x8 bf1 = *(const f16x8*)&Bl[wc*32 + 16 + lr][kf*32 + lg*8];
      acc[0][0] = mfma16(af0, bf0, acc[0][0]);
      acc[0][1] = mfma16(af0, bf1, acc[0][1]);
      acc[1][0] = mfma16(af1, bf0, acc[1][0]);
      acc[1][1] = mfma16(af1, bf1, acc[1][1]);
    }
  }
  #pragma unroll
  for (int j = 0; j < 2; j++) {
    const int oc = o0 + wc*32 + j*16 + lr;
    const float bo = bias ? bias[oc] : 0.f;
    #pragma unroll
    for (int i = 0; i < 2; i++) {
      const int nb = n0 + wr*32 + i*16 + lg*4;
      #pragma unroll
      for (int r = 0; r < 4; r++)
        out[((long)b*NN + nb + r)*ocols + oc] = f2h(acc[i][j][r] + bo);
    }
  }
}

// ---------------------------------------------------------------------------
// GEMM (W-major o): out[o][n] = sum_c W[o][c]*X[n][c] + bias[o]; f16 [B][CC][NN]
// ---------------------------------------------------------------------------
__global__ __launch_bounds__(256)
void gemm_wx_kernel(const unsigned short* __restrict__ W,
                    const unsigned short* __restrict__ X,
                    const float* __restrict__ bias,
                    unsigned short* __restrict__ out)
{
  const int n0 = blockIdx.x*64, o0 = blockIdx.y*64, b = blockIdx.z;
  const int t = threadIdx.x;
  const int w = t >> 6, l = t & 63, lr = l & 15, lg = l >> 4;
  const int wr = w >> 1, wc = w & 1;
  __shared__ unsigned short Al[64][72];
  __shared__ unsigned short Bl[64][72];
  const unsigned short* Xb = X + ((long)b*NN + n0)*CC;
  const int srow = t >> 3, sg = t & 7;
  f32x4 acc[2][2];
  #pragma unroll
  for (int i = 0; i < 2; i++)
    #pragma unroll
    for (int j = 0; j < 2; j++) acc[i][j] = f32x4{0.f,0.f,0.f,0.f};

  for (int kt = 0; kt < 4; kt++) {
    const int k0 = kt*64;
    const uint4 w0 = *(const uint4*)&W[(long)(o0+srow)*CC + k0 + sg*8];
    const uint4 w1 = *(const uint4*)&W[(long)(o0+srow+32)*CC + k0 + sg*8];
    const uint4 x0 = *(const uint4*)&Xb[(long)srow*CC + k0 + sg*8];
    const uint4 x1 = *(const uint4*)&Xb[(long)(srow+32)*CC + k0 + sg*8];
    __syncthreads();
    *(uint4*)&Al[srow][sg*8] = w0;  *(uint4*)&Al[srow+32][sg*8] = w1;
    *(uint4*)&Bl[srow][sg*8] = x0;  *(uint4*)&Bl[srow+32][sg*8] = x1;
    __syncthreads();
    #pragma unroll
    for (int kf = 0; kf < 2; kf++) {
      f16x8 af0 = *(const f16x8*)&Al[wr*32 + lr]     [kf*32 + lg*8];
      f16x8 af1 = *(const f16x8*)&Al[wr*32 + 16 + lr][kf*32 + lg*8];
      f16x8 bf0 = *(const f16x8*)&Bl[wc*32 + lr]     [kf*32 + lg*8];
      f16x8 bf1 = *(const f16x8*)&Bl[wc*32 + 16 + lr][kf*32 + lg*8];
      acc[0][0] = mfma16(af0, bf0, acc[0][0]);
      acc[0][1] = mfma16(af0, bf1, acc[0][1]);
      acc[1][0] = mfma16(af1, bf0, acc[1][0]);
      acc[1][1] = mfma16(af1, bf1, acc[1][1]);
    }
  }
  #pragma unroll
  for (int j = 0; j < 2; j++) {
    const int nc = n0 + wc*32 + j*16 + lr;
    #pragma unroll
    for (int i = 0; i < 2; i++) {
      #pragma unroll
      for (int r = 0; r < 4; r++) {
        const int oc = o0 + wr*32 + i*16 + lg*4 + r;
        out[((long)b*CC + oc)*NN + nc] = f2h(acc[i][j][r] + bias[oc]);
      }
    }
  }
}

// ---------------------------------------------------------------------------
// rowstat: per (b,n): max_m / 1/sum_m of exp(masked S[n,m]).
// Swizzled single 8KB q tile (A regs hoisted), tile-max deferred exp.
// 1D grid 512, XCD-swizzled.
// ---------------------------------------------------------------------------
__global__ __launch_bounds__(256)
void rowstat_kernel(const unsigned short* __restrict__ qT, const int* __restrict__ mask,
                    float* __restrict__ rmax, float* __restrict__ rinv)
{
  const int bid = blockIdx.x;
  const int swz = (bid & 7)*64 + (bid >> 3);   // 512 = 8 XCDs x 64
  const int b  = swz >> 5;
  const int n0 = (swz & 31) * 64;
  const int t = threadIdx.x, w = t>>6, l = t&63, lr = l&15, lg = l>>4;
  __shared__ unsigned short qs[64*64];
  __shared__ int ml[64];
  const int srow = t>>3, sg = t&7;
  const unsigned short* qbase = qT + (long)b*NN*HH;
  *(uint4*)sp(qs, srow,    sg*8) = *(const uint4*)&qbase[(long)(n0+srow)*HH + sg*8];
  *(uint4*)sp(qs, srow+32, sg*8) = *(const uint4*)&qbase[(long)(n0+srow+32)*HH + sg*8];
  int maskn[4];
  #pragma unroll
  for (int r = 0; r < 4; r++) maskn[r] = mask[(long)b*NN + n0 + w*16 + lg*4 + r];
  __syncthreads();
  f16x8 af0 = *(const f16x8*)spc(qs, w*16 + lr, lg*8);
  f16x8 af1 = *(const f16x8*)spc(qs, w*16 + lr, 32 + lg*8);
  float mx[4], sm[4];
  #pragma unroll
  for (int r = 0; r < 4; r++) { mx[r] = -INFINITY; sm[r] = 0.f; }

  for (int m0 = 0; m0 < NN; m0 += 64) {
    __syncthreads();
    *(uint4*)sp(qs, srow,    sg*8) = *(const uint4*)&qbase[(long)(m0+srow)*HH + sg*8];
    *(uint4*)sp(qs, srow+32, sg*8) = *(const uint4*)&qbase[(long)(m0+srow+32)*HH + sg*8];
    if (t < 64) ml[t] = mask[(long)b*NN + m0 + t];
    __syncthreads();
    float sv[4][4];
    #pragma unroll
    for (int tm = 0; tm < 4; tm++) {
      f32x4 s = f32x4{0.f,0.f,0.f,0.f};
      s = mfma16(af0, *(const f16x8*)spc(qs, tm*16 + lr, lg*8),      s);
      s = mfma16(af1, *(const f16x8*)spc(qs, tm*16 + lr, 32 + lg*8), s);
      const int cm = ml[tm*16 + lr];
      #pragma unroll
      for (int r = 0; r < 4; r++) sv[tm][r] = (maskn[r] && cm) ? s[r] : NEGV;
    }
    #pragma unroll
    for (int r = 0; r < 4; r++) {
      const float tmx = fmaxf(fmaxf(sv[0][r], sv[1][r]), fmaxf(sv[2][r], sv[3][r]));
      const float nm  = fmaxf(mx[r], tmx);
      sm[r] = sm[r]*__expf(mx[r]-nm)
            + __expf(sv[0][r]-nm) + __expf(sv[1][r]-nm)
            + __expf(sv[2][r]-nm) + __expf(sv[3][r]-nm);
      mx[r] = nm;
    }
  }
  #pragma unroll
  for (int off = 1; off < 16; off <<= 1) {
    #pragma unroll
    for (int r = 0; r < 4; r++) {
      const float om = __shfl_xor(mx[r], off, 64);
      const float os = __shfl_xor(sm[r], off, 64);
      const float nm = fmaxf(mx[r], om);
      sm[r] = sm[r]*__expf(mx[r]-nm) + os*__expf(om-nm);
      mx[r] = nm;
    }
  }
  if (lr == 0) {
    #pragma unroll
    for (int r = 0; r < 4; r++) {
      const long idx = (long)b*NN + n0 + w*16 + lg*4 + r;
      rmax[idx] = mx[r];
      rinv[idx] = 1.f/sm[r];
    }
  }
}

// ---------------------------------------------------------------------------
// yatt: x_rT[m][c] (f16) = sum_n xv[c][n]*Atil[n][m]; csum[m] = sum_n Atil[n][m].
// S phase: waves split m (16 rows each). PV: waves split c (64 each), xv B-frags
// read straight from global (L2-resident via XCD swizzle), at via swizzled LDS.
// LDS 17KB, 1D grid 512.
// ---------------------------------------------------------------------------
__global__ __launch_bounds__(256)
void yatt_kernel(const unsigned short* __restrict__ qT, const unsigned short* __restrict__ xv,
                 const int* __restrict__ mask, const float* __restrict__ rmax,
                 const float* __restrict__ rinv, unsigned short* __restrict__ xrTh,
                 float* __restrict__ csum)
{
  const int bid = blockIdx.x;
  const int swz = (bid & 7)*64 + (bid >> 3);
  const int b  = swz >> 5;
  const int m0 = (swz & 31) * 64;
  const int t = threadIdx.x, w = t>>6, l = t&63, lr = l&15, lg = l>>4;
  __shared__ unsigned short qn[64*64];
  __shared__ unsigned short at[64*64];   // doubles as qm staging at start
  __shared__ float rml[64], ril[64];
  __shared__ int mrl[64];
  const int srow = t>>3, sg = t&7;
  const unsigned short* qbase = qT + (long)b*NN*HH;
  const unsigned short* xvb = xv + (long)b*CC*NN;

  *(uint4*)sp(at, srow,    sg*8) = *(const uint4*)&qbase[(long)(m0+srow)*HH + sg*8];
  *(uint4*)sp(at, srow+32, sg*8) = *(const uint4*)&qbase[(long)(m0+srow+32)*HH + sg*8];
  int maskm[4];
  #pragma unroll
  for (int r = 0; r < 4; r++) maskm[r] = mask[(long)b*NN + m0 + w*16 + lg*4 + r];
  __syncthreads();
  f16x8 am0 = *(const f16x8*)spc(at, w*16 + lr, lg*8);
  f16x8 am1 = *(const f16x8*)spc(at, w*16 + lr, 32 + lg*8);

  f32x4 acc[4][4];
  #pragma unroll
  for (int mi = 0; mi < 4; mi++)
    #pragma unroll
    for (int ci = 0; ci < 4; ci++) acc[mi][ci] = f32x4{0.f,0.f,0.f,0.f};
  float cs[4] = {0.f, 0.f, 0.f, 0.f};

  for (int nc = 0; nc < NN; nc += 64) {
    __syncthreads();   // prev chunk's PV (at) / S (qn) readers done
    *(uint4*)sp(qn, srow,    sg*8) = *(const uint4*)&qbase[(long)(nc+srow)*HH + sg*8];
    *(uint4*)sp(qn, srow+32, sg*8) = *(const uint4*)&qbase[(long)(nc+srow+32)*HH + sg*8];
    if (t < 64) {
      rml[t] = rmax[(long)b*NN + nc + t];
      ril[t] = rinv[(long)b*NN + nc + t];
      mrl[t] = mask[(long)b*NN + nc + t];
    }
    // global xv B-fragments for this wave's c slice (L2-resident)
    f16x8 xb0[4], xb1[4];
    #pragma unroll
    for (int ci = 0; ci < 4; ci++) {
      const unsigned short* xp = &xvb[(long)(w*64 + ci*16 + lr)*NN + nc];
      xb0[ci] = *(const f16x8*)(xp + lg*8);
      xb1[ci] = *(const f16x8*)(xp + 32 + lg*8);
    }
    __syncthreads();
    // S phase: energy -> exp -> at (scaled f16, swizzled)
    #pragma unroll
    for (int tn = 0; tn < 4; tn++) {
      f32x4 s = f32x4{0.f,0.f,0.f,0.f};
      s = mfma16(am0, *(const f16x8*)spc(qn, tn*16 + lr, lg*8),      s);
      s = mfma16(am1, *(const f16x8*)spc(qn, tn*16 + lr, 32 + lg*8), s);
      const int nn = tn*16 + lr;
      const int cm = mrl[nn];
      const float rm = rml[nn], ri = ril[nn];
      #pragma unroll
      for (int r = 0; r < 4; r++) {
        const float vm = (maskm[r] && cm) ? s[r] : NEGV;
        const float a_ = __expf(vm - rm) * ri;
        cs[r] += a_;
        *sp(at, w*16 + lg*4 + r, nn) = f2h(a_ * ATTSC);
      }
    }
    __syncthreads();   // at complete before cross-wave PV reads
    // PV: wave w owns c = w*64..+64, all 64 m
    {
      f16x8 aa[4];
      #pragma unroll
      for (int mi = 0; mi < 4; mi++) aa[mi] = *(const f16x8*)spc(at, mi*16 + lr, lg*8);
      #pragma unroll
      for (int ci = 0; ci < 4; ci++)
        #pragma unroll
        for (int mi = 0; mi < 4; mi++)
          acc[mi][ci] = mfma16(aa[mi], xb0[ci], acc[mi][ci]);
      #pragma unroll
      for (int mi = 0; mi < 4; mi++) aa[mi] = *(const f16x8*)spc(at, mi*16 + lr, 32 + lg*8);
      #pragma unroll
      for (int ci = 0; ci < 4; ci++)
        #pragma unroll
        for (int mi = 0; mi < 4; mi++)
          acc[mi][ci] = mfma16(aa[mi], xb1[ci], acc[mi][ci]);
    }
  }
  #pragma unroll
  for (int mi = 0; mi < 4; mi++)
    #pragma unroll
    for (int ci = 0; ci < 4; ci++)
      #pragma unroll
      for (int r = 0; r < 4; r++)
        xrTh[((long)b*NN + m0 + mi*16 + lg*4 + r)*CC + w*64 + ci*16 + lr] =
            f2h(acc[mi][ci][r] * ATTINV);
  #pragma unroll
  for (int off = 1; off < 16; off <<= 1) {
    #pragma unroll
    for (int r = 0; r < 4; r++) cs[r] += __shfl_xor(cs[r], off, 64);
  }
  if (lr == 0) {
    #pragma unroll
    for (int r = 0; r < 4; r++)
      csum[(long)b*NN + m0 + w*16 + lg*4 + r] = cs[r];
  }
}

// ---------------------------------------------------------------------------
// diff: dT[p][c] = f16( xT[p][c] - xrTh[p][c]/(1e-9 + csum[p]) )
// ---------------------------------------------------------------------------
__global__ __launch_bounds__(256)
void diff_kernel(const unsigned short* __restrict__ xT, const unsigned short* __restrict__ xrTh,
                 const float* __restrict__ csumv, unsigned short* __restrict__ dT)
{
  const long i = (long)blockIdx.x*256 + threadIdx.x;
  const long base = i*8;
  const long row = base >> 8;
  const float inv = 1.f/(1e-9f + csumv[row]);
  const uint4 xu = *(const uint4*)&xT[base];
  const uint4 yu = *(const uint4*)&xrTh[base];
  const unsigned short* xs = (const unsigned short*)&xu;
  const unsigned short* ys = (const unsigned short*)&yu;
  uint4 ou;
  unsigned short* os = (unsigned short*)&ou;
  #pragma unroll
  for (int j = 0; j < 8; j++) os[j] = f2h(h2f(xs[j]) - h2f(ys[j])*inv);
  *(uint4*)&dT[base] = ou;
}

// ---------------------------------------------------------------------------
// BN stats over [B*N][C] f16, two-stage deterministic
// ---------------------------------------------------------------------------
__global__ __launch_bounds__(256)
void bnstatsA_kernel(const unsigned short* __restrict__ tTh, float* __restrict__ part)
{
  const int k = blockIdx.x;      // 256 blocks x 128 rows
  const int c = threadIdx.x;
  float s = 0.f, sq = 0.f;
  const long r0 = (long)k*128;
  for (int r = 0; r < 128; r++) {
    const float v = h2f(tTh[(r0 + r)*CC + c]);
    s += v; sq += v*v;
  }
  part[(long)k*CC + c] = s;
  part[(long)(256 + k)*CC + c] = sq;
}

__global__ __launch_bounds__(1024)
void bnstatsB_kernel(const float* __restrict__ part,
                     float* __restrict__ mean, float* __restrict__ istd)
{
  const int t = threadIdx.x, c = t & 255, q = t >> 8;
  float s = 0.f, sq = 0.f;
  for (int k = q*64; k < q*64 + 64; k++) {
    s  += part[(long)k*CC + c];
    sq += part[(long)(256 + k)*CC + c];
  }
  __shared__ float ls[4][256], lq[4][256];
  ls[q][c] = s; lq[q][c] = sq;
  __syncthreads();
  if (q == 0) {
    s  = ls[0][c] + ls[1][c] + ls[2][c] + ls[3][c];
    sq = lq[0][c] + lq[1][c] + lq[2][c] + lq[3][c];
    const float mu = s / (float)(BB*NN);
    mean[c] = mu;
    istd[c] = rsqrtf(sq/(float)(BB*NN) - mu*mu + 1e-5f);
  }
}

// ---------------------------------------------------------------------------
// bnapplyA: xTo[p][c] = f16(relu(bn(tTh[p][c])))  ([N][C] layout, no resid)
// ---------------------------------------------------------------------------
__global__ __launch_bounds__(256)
void bnapplyA_kernel(const unsigned short* __restrict__ tTh, const float* __restrict__ mean,
                     const float* __restrict__ istd, const float* __restrict__ g,
                     const float* __restrict__ bt, unsigned short* __restrict__ xTo)
{
  __shared__ float sc[CC], sh[CC];
  const int t = threadIdx.x;
  {
    const float is = istd[t], gg = g[t];
    sc[t] = is*gg; sh[t] = bt[t] - mean[t]*is*gg;
  }
  __syncthreads();
  const long i = (long)blockIdx.x*256 + t;
  const long base = i*8;
  const int c8 = (int)(base & 255);
  const uint4 v = *(const uint4*)&tTh[base];
  const unsigned short* hs = (const unsigned short*)&v;
  uint4 ou;
  unsigned short* os = (unsigned short*)&ou;
  #pragma unroll
  for (int j = 0; j < 8; j++)
    os[j] = f2h(fmaxf(h2f(hs[j])*sc[c8+j] + sh[c8+j], 0.f));
  *(uint4*)&xTo[base] = ou;
}

// ---------------------------------------------------------------------------
// bnfuse: from tTh f16 [n][c]: out fp32 [c][n] = relu(bn)+resid, and
// (optional) xtn f16 [n][c] = same value  — replaces bnapplyT + tcast.
// ---------------------------------------------------------------------------
__global__ __launch_bounds__(256)
void bnfuse_kernel(const unsigned short* __restrict__ tTh, const float* __restrict__ mean,
                   const float* __restrict__ istd, const float* __restrict__ g,
                   const float* __restrict__ bt, const float* __restrict__ resid,
                   long rstride, float* __restrict__ outp, long ostride,
                   unsigned short* __restrict__ xtn)
{
  const int b = blockIdx.z, n0 = blockIdx.x*64, c0 = blockIdx.y*64;
  const int t = threadIdx.x;
  __shared__ float tile[64][66];   // [c][n]
  const unsigned short* tb_ = tTh + ((long)b*NN + n0)*CC;
  const int cq = (t&15)*4;
  float scv[4], shv[4];
  #pragma unroll
  for (int j = 0; j < 4; j++) {
    const int c = c0 + cq + j;
    const float is = istd[c], gg = g[c];
    scv[j] = is*gg; shv[j] = bt[c] - mean[c]*is*gg;
  }
  #pragma unroll
  for (int p = 0; p < 4; p++) {
    const int nr = (t>>4) + p*16;
    const ushort4 v = *(const ushort4*)&tb_[(long)nr*CC + c0 + cq];
    tile[cq+0][nr] = fmaxf(h2f(v.x)*scv[0] + shv[0], 0.f);
    tile[cq+1][nr] = fmaxf(h2f(v.y)*scv[1] + shv[1], 0.f);
    tile[cq+2][nr] = fmaxf(h2f(v.z)*scv[2] + shv[2], 0.f);
    tile[cq+3][nr] = fmaxf(h2f(v.w)*scv[3] + shv[3], 0.f);
  }
  __syncthreads();
  const int nq = (t&15)*4;
  #pragma unroll
  for (int p = 0; p < 4; p++) {
    const int cr = (t>>4) + p*16;
    float4 o;
    o.x = tile[cr][nq+0]; o.y = tile[cr][nq+1];
    o.z = tile[cr][nq+2]; o.w = tile[cr][nq+3];
    if (resid) {
      const float4 rv = *(const float4*)&resid[(long)b*rstride + (long)(c0+cr)*NN + n0 + nq];
      o.x += rv.x; o.y += rv.y; o.z += rv.z; o.w += rv.w;
    }
    *(float4*)&outp[(long)b*ostride + (long)(c0+cr)*NN + n0 + nq] = o;
    tile[cr][nq+0] = o.x; tile[cr][nq+1] = o.y;
    tile[cr][nq+2] = o.z; tile[cr][nq+3] = o.w;
  }
  if (xtn) {
    __syncthreads();
    #pragma unroll
    for (int p = 0; p < 4; p++) {
      const int nr = (t>>4) + p*16;
      ushort4 o;
      o.x = f2h(tile[cq+0][nr]); o.y = f2h(tile[cq+1][nr]);
      o.z = f2h(tile[cq+2][nr]); o.w = f2h(tile[cq+3][nr]);
      *(ushort4*)&xtn[((long)b*NN + n0+nr)*CC + c0 + cq] = o;
    }
  }
}

// ---------------------------------------------------------------------------
extern "C" void kernel_launch(void* const* d_in, const int* in_sizes, int n_in,
                              void* d_out, int out_size, void* d_ws, size_t ws_size,
                              hipStream_t stream)
{
  const float* x_in   = (const float*)d_in[0];
  const int*   mask   = (const int*)d_in[1];
  const float* conv1w = (const float*)d_in[2];
  const float* conv2w = (const float*)d_in[3];
  const float* bn1g   = (const float*)d_in[4];
  const float* bn1b   = (const float*)d_in[5];
  const float* bn2g   = (const float*)d_in[6];
  const float* bn2b   = (const float*)d_in[7];
  const float* qkw    = (const float*)d_in[8];
  const float* vw     = (const float*)d_in[9];
  const float* vb     = (const float*)d_in[10];
  const float* tw     = (const float*)d_in[11];
  const float* tb     = (const float*)d_in[12];
  const float* bng    = (const float*)d_in[13];
  const float* bnb    = (const float*)d_in[14];
  float* out = (float*)d_out;

  const long BCN = (long)BB*CC*NN;
  const long CN  = (long)CC*NN;
  char* p = (char*)d_ws;
  unsigned short* xTa  = (unsigned short*)p; p += BCN*2;
  unsigned short* xTb  = (unsigned short*)p; p += BCN*2;
  unsigned short* qTb  = (unsigned short*)p; p += (long)BB*NN*HH*2;
  unsigned short* xvb  = (unsigned short*)p; p += BCN*2;   // aliased as dT
  unsigned short* tTh  = (unsigned short*)p; p += BCN*2;
  unsigned short* xrTh = (unsigned short*)p; p += BCN*2;
  float* xbuf  = (float*)p; p += BCN*4;
  float* rmaxb = (float*)p; p += (long)BB*NN*4;
  float* rinvb = (float*)p; p += (long)BB*NN*4;
  float* csumb = (float*)p; p += (long)BB*NN*4;
  float* partb = (float*)p; p += 512L*CC*4;
  float* meanb = (float*)p; p += CC*4;
  float* istdb = (float*)p; p += CC*4;
  unsigned short* wc1 = (unsigned short*)p; p += (long)CC*CC*2;
  unsigned short* wc2 = (unsigned short*)p; p += (long)CC*CC*2;
  unsigned short* wqk = (unsigned short*)p; p += 4L*HH*CC*2;
  unsigned short* wv  = (unsigned short*)p; p += 4L*CC*CC*2;
  unsigned short* wt  = (unsigned short*)p; p += 4L*CC*CC*2;

  const dim3 gT(NN/64, CC/64, BB);      // 32,4,16
  const dim3 gQ(NN/64, 1, BB);
  const dim3 gAtt(512);                 // 1D, XCD-swizzled in-kernel
  const dim3 blk(256);

  castw_kernel<<<dim3(256), blk, 0, stream>>>(conv1w, wc1, CC*CC);
  castw_kernel<<<dim3(256), blk, 0, stream>>>(conv2w, wc2, CC*CC);
  castw_kernel<<<dim3(256), blk, 0, stream>>>(qkw, wqk, 4*HH*CC);
  castw_kernel<<<dim3(1024), blk, 0, stream>>>(vw, wv, 4*CC*CC);
  castw_kernel<<<dim3(1024), blk, 0, stream>>>(tw, wt, 4*CC*CC);

  // pre-stage
  tcast_kernel<<<gT, blk, 0, stream>>>(x_in, CN, xTa);
  gemm_xw_kernel<<<gT, blk, 0, stream>>>(xTa, wc1, nullptr, tTh, CC);
  bnstatsA_kernel<<<dim3(256), blk, 0, stream>>>(tTh, partb);
  bnstatsB_kernel<<<dim3(1), dim3(1024), 0, stream>>>(partb, meanb, istdb);
  bnapplyA_kernel<<<dim3(4096), blk, 0, stream>>>(tTh, meanb, istdb, bn1g, bn1b, xTb);
  gemm_xw_kernel<<<gT, blk, 0, stream>>>(xTb, wc2, nullptr, tTh, CC);
  bnstatsA_kernel<<<dim3(256), blk, 0, stream>>>(tTh, partb);
  bnstatsB_kernel<<<dim3(1), dim3(1024), 0, stream>>>(partb, meanb, istdb);
  bnfuse_kernel<<<gT, blk, 0, stream>>>(tTh, meanb, istdb, bn2g, bn2b,
                                        nullptr, 0, xbuf, CN, xTa);

  unsigned short* cur = xTa;
  unsigned short* nxt = xTb;
  for (int i = 0; i < 4; i++) {
    gemm_xw_kernel<<<gQ, blk, 0, stream>>>(cur, wqk + (long)i*HH*CC, nullptr, qTb, HH);
    rowstat_kernel<<<gAtt, blk, 0, stream>>>(qTb, mask, rmaxb, rinvb);
    gemm_wx_kernel<<<gT, blk, 0, stream>>>(wv + (long)i*CC*CC, cur, vb + (long)i*CC, xvb);
    yatt_kernel<<<gAtt, blk, 0, stream>>>(qTb, xvb, mask, rmaxb, rinvb, xrTh, csumb);
    diff_kernel<<<dim3(4096), blk, 0, stream>>>(cur, xrTh, csumb, xvb);
    gemm_xw_kernel<<<gT, blk, 0, stream>>>(xvb, wt + (long)i*CC*CC, tb + (long)i*CC, tTh, CC);
    bnstatsA_kernel<<<dim3(256), blk, 0, stream>>>(tTh, partb);
    bnstatsB_kernel<<<dim3(1), dim3(1024), 0, stream>>>(partb, meanb, istdb);
    const float* resid = (i == 0) ? xbuf : (out + (long)(i-1)*CN);
    const long rstr = (i == 0) ? CN : 4*CN;
    bnfuse_kernel<<<gT, blk, 0, stream>>>(tTh, meanb, istdb,
                                          bng + (long)i*CC, bnb + (long)i*CC,
                                          resid, rstr, out + (long)i*CN, 4*CN,
                                          (i < 3) ? nxt : nullptr);
    unsigned short* tmp = cur; cur = nxt; nxt = tmp;
  }

  (void)in_sizes; (void)n_in; (void)out_size; (void)ws_size;
}